// Round 12
// baseline (202.323 us; speedup 1.0000x reference)
//
#include <hip/hip_runtime.h>
#include <hip/hip_bf16.h>

// ContrastiveLoss on MI355X.
// ws layout (requires ws_size >= 8MB + 96KB):
//   [0, 4MB)        xn bf16 [8192][256]
//   [4MB, 8MB)      yn bf16 [8192][256]
//   [8MB, 8MB+96KB) rowsum f32 [3][8192]

#define N_ROWS 8192
#define DIM 256
#define EPSF 1e-8f
#define BM 128
#define BK 64
#define TILE (BM * BK)   // 8192 shorts = 16KB

typedef __attribute__((ext_vector_type(8))) short bf16x8;
typedef __attribute__((ext_vector_type(4))) float f32x4;
typedef __attribute__((ext_vector_type(4))) short short4v;

__device__ __forceinline__ short f2bf(float f) {
  unsigned u = __float_as_uint(f);
  unsigned r = (u + 0x7fffu + ((u >> 16) & 1u)) >> 16;  // RNE
  return (short)r;
}

__device__ __forceinline__ float bf2f(short s) {
  return __uint_as_float(((unsigned)(unsigned short)s) << 16);
}

typedef const __attribute__((address_space(1))) void g_void;
typedef __attribute__((address_space(3))) void s_void;

__device__ __forceinline__ void gld_lds16(const void* g, void* l) {
  __builtin_amdgcn_global_load_lds((g_void*)g, (s_void*)l, 16, 0, 0);
}

// ---- Kernel 1: row-normalize x,y -> bf16; also zero rowsum and out ----
__global__ void k_normalize(const float* __restrict__ x, const float* __restrict__ y,
                            short* __restrict__ xn, short* __restrict__ yn,
                            float* __restrict__ rowsum, float* __restrict__ out) {
  if (blockIdx.x < 96) rowsum[blockIdx.x * 256 + threadIdx.x] = 0.f;  // 96*256 = 24576
  if (blockIdx.x == 96 && threadIdx.x == 0) out[0] = 0.f;

  int wave = threadIdx.x >> 6;
  int lane = threadIdx.x & 63;
  int row = blockIdx.x * 4 + wave;  // 0..16383
  const float* src;
  short* dst;
  int r;
  if (row < N_ROWS) { src = x; dst = xn; r = row; }
  else              { src = y; dst = yn; r = row - N_ROWS; }
  const float4 v = *(const float4*)(src + r * DIM + lane * 4);
  float ss = v.x * v.x + v.y * v.y + v.z * v.z + v.w * v.w;
  #pragma unroll
  for (int m = 1; m < 64; m <<= 1) ss += __shfl_xor(ss, m, 64);
  float scale = 1.0f / (sqrtf(ss) + EPSF);
  short4v o;
  o.x = f2bf(v.x * scale);
  o.y = f2bf(v.y * scale);
  o.z = f2bf(v.z * scale);
  o.w = f2bf(v.w * scale);
  *(short4v*)(dst + r * DIM + lane * 4) = o;
}

// ------- Kernel 2: sim tile (bf16 MFMA) + exp + row/col partial sums -------
// m97/m103-exact structure: 128^2 tile, BK=64, SINGLE-buffered (stage->sync->
// compute->sync), 33KB LDS -> 4 blocks/CU. Residency law from r5-r9 counters:
// MfmaUtil ~= 9-10% x blocks/CU; explicit dbuf halves residency for no gain
// (m99/m100/m132). 128^2 > 128x256 > 256^2 at this structure (m103/105/112).
// Conflict-free involution cs = c^(row&7) (r7-verified: SQ_LDS_BANK_CONFLICT=0).
// Compact grid 8256 = 2*2080 upper-tri + 4096 xy = 8*1032 (exact XCD balance).
__global__ __launch_bounds__(256, 4) void k_gemm(const short* __restrict__ xn,
                                                 const short* __restrict__ yn,
                                                 float* __restrict__ rowsum) {
  __shared__ __align__(16) short As[TILE];   // 16KB
  __shared__ __align__(16) short Bs[TILE];   // 16KB
  __shared__ float redbuf[256];              // 1KB

  int bid = blockIdx.x;
  int swz = (bid & 7) * 1032 + (bid >> 3);  // XCD-chunked, bijective (8256%8==0)

  // unrank compact id -> (pair, mb, nb)
  int pair, mb, nb;
  if (swz < 4160) {                         // symmetric pairs, upper triangle
    pair = (swz < 2080) ? 0 : 2;
    int t = (swz < 2080) ? swz : swz - 2080;
    int r = 0;
    while (t >= 64 - r) { t -= 64 - r; ++r; }  // block-uniform, <=64 iters
    mb = r; nb = r + t;
  } else {                                  // xy: full 64x64
    pair = 1;
    int t = swz - 4160;
    mb = t >> 6; nb = t & 63;
  }

  const short* Ap = (pair == 2) ? yn : xn;
  const short* Bp = (pair == 0) ? xn : yn;
  const short* Abase = Ap + mb * BM * DIM;
  const short* Bbase = Bp + nb * BM * DIM;

  int tid = threadIdx.x;
  int lane = tid & 63;
  int wid = tid >> 6;
  int wm = wid >> 1, wn = wid & 1;

  redbuf[tid] = 0.f;  // ordered by the K-loop barriers before epilogue use

  f32x4 acc[4][4];
  #pragma unroll
  for (int i = 0; i < 4; ++i)
    #pragma unroll
    for (int j = 0; j < 4; ++j) acc[i][j] = (f32x4){0.f, 0.f, 0.f, 0.f};

  // stage [128][64] A,B tiles; LDS 16B-slot (row,c) holds global chunk
  // c ^ (row&7)  (linear gld_lds dest per rule #21; involution on read)
  auto stage = [&](int koff) {
    #pragma unroll
    for (int i = 0; i < 4; ++i) {
      int s = i * 256 + tid;         // 16B slot id, 1024 slots per tile
      int row = s >> 3, c = s & 7;
      int cs = c ^ (row & 7);
      gld_lds16(Abase + row * DIM + koff + cs * 8, As + s * 8);
      gld_lds16(Bbase + row * DIM + koff + cs * 8, Bs + s * 8);
    }
  };

  auto compute = [&]() {
    #pragma unroll
    for (int kk = 0; kk < 2; ++kk) {
      bf16x8 a[4], b[4];
      int slot = (kk * 4 + (lane >> 4)) ^ (lane & 7);  // swizzled 16B slot
      #pragma unroll
      for (int mi = 0; mi < 4; ++mi) {
        int row = wm * 64 + mi * 16 + (lane & 15);     // row&7 == lane&7
        a[mi] = *(const bf16x8*)(As + row * BK + slot * 8);
      }
      #pragma unroll
      for (int ni = 0; ni < 4; ++ni) {
        int row = wn * 64 + ni * 16 + (lane & 15);
        b[ni] = *(const bf16x8*)(Bs + row * BK + slot * 8);
      }
      #pragma unroll
      for (int mi = 0; mi < 4; ++mi)
        #pragma unroll
        for (int ni = 0; ni < 4; ++ni)
          acc[mi][ni] = __builtin_amdgcn_mfma_f32_16x16x32_bf16(a[mi], b[ni], acc[mi][ni], 0, 0, 0);
    }
  };

  // single-buffered K-loop over DIM/BK = 4 steps (cross-block TLP hides drains)
  #pragma unroll
  for (int ks = 0; ks < 4; ++ks) {
    stage(ks * BK);
    __syncthreads();
    compute();
    if (ks < 3) __syncthreads();
  }

  // epilogue: exp in place, then row sums (and col sums for sym off-diag)
  // C layout (m89): col = lane&15, row = (lane>>4)*4 + r
  // global: row = mb*128 + wm*64 + mi*16 + (lane>>4)*4 + r
  //         col = nb*128 + wn*64 + ni*16 + (lane&15)
  #pragma unroll
  for (int mi = 0; mi < 4; ++mi)
    #pragma unroll
    for (int ni = 0; ni < 4; ++ni)
      #pragma unroll
      for (int r = 0; r < 4; ++r)
        acc[mi][ni][r] = __expf(acc[mi][ni][r]);

  float rs[4][4];
  #pragma unroll
  for (int mi = 0; mi < 4; ++mi)
    #pragma unroll
    for (int r = 0; r < 4; ++r)
      rs[mi][r] = acc[mi][0][r] + acc[mi][1][r] + acc[mi][2][r] + acc[mi][3][r];
  #pragma unroll
  for (int m = 1; m < 16; m <<= 1)
    #pragma unroll
    for (int mi = 0; mi < 4; ++mi)
      #pragma unroll
      for (int r = 0; r < 4; ++r) rs[mi][r] += __shfl_xor(rs[mi][r], m, 64);
  if ((lane & 15) == 0) {
    int rloc = wm * 64 + (lane >> 4) * 4;
    #pragma unroll
    for (int mi = 0; mi < 4; ++mi)
      #pragma unroll
      for (int r = 0; r < 4; ++r)
        atomicAdd(&redbuf[rloc + mi * 16 + r], rs[mi][r]);   // 2-way (wn) combine
  }

  bool do_cols = (pair != 1) && (nb > mb);
  if (do_cols) {
    float cs[4];
    #pragma unroll
    for (int ni = 0; ni < 4; ++ni) {
      cs[ni] = 0.f;
      #pragma unroll
      for (int mi = 0; mi < 4; ++mi)
        #pragma unroll
        for (int r = 0; r < 4; ++r) cs[ni] += acc[mi][ni][r];
    }
    #pragma unroll
    for (int m = 16; m < 64; m <<= 1)
      #pragma unroll
      for (int ni = 0; ni < 4; ++ni) cs[ni] += __shfl_xor(cs[ni], m, 64);
    if (lane < 16) {
      #pragma unroll
      for (int ni = 0; ni < 4; ++ni)
        atomicAdd(&redbuf[128 + wn * 64 + ni * 16 + lane], cs[ni]);  // 2-way (wm)
    }
  }
  __syncthreads();

  // one global atomic per row / per col for the whole block
  if (tid < 128)
    atomicAdd(&rowsum[pair * N_ROWS + mb * BM + tid], redbuf[tid]);
  else if (do_cols)
    atomicAdd(&rowsum[pair * N_ROWS + nb * BM + (tid - 128)], redbuf[tid]);
}

// ------- Kernel 3: loss = sum over rows of log(S) - pos -------
__global__ void k_reduce(const short* __restrict__ xn, const short* __restrict__ yn,
                         const float* __restrict__ rowsum, float* __restrict__ out) {
  int tid = threadIdx.x, lane = tid & 63, wid = tid >> 6;
  int gw = blockIdx.x * 4 + wid;  // 0..1023
  float acc = 0.f;
  for (int r = gw; r < 3 * N_ROWS; r += 1024) {
    int pair = r / N_ROWS;
    int n = r - pair * N_ROWS;
    const short* a = (pair == 2) ? yn : xn;
    const short* b = (pair == 0) ? xn : yn;
    short4v av = *(const short4v*)(a + n * DIM + lane * 4);
    short4v bv = *(const short4v*)(b + n * DIM + lane * 4);
    float dot = bf2f(av.x) * bf2f(bv.x) + bf2f(av.y) * bf2f(bv.y) +
                bf2f(av.z) * bf2f(bv.z) + bf2f(av.w) * bf2f(bv.w);
    #pragma unroll
    for (int m = 1; m < 64; m <<= 1) dot += __shfl_xor(dot, m, 64);
    if (lane == 0) acc += logf(rowsum[r]) - dot;
  }
  __shared__ float tmp[4];
  if (lane == 0) tmp[wid] = acc;
  __syncthreads();
  if (tid == 0) atomicAdd(out, tmp[0] + tmp[1] + tmp[2] + tmp[3]);
}

extern "C" void kernel_launch(void* const* d_in, const int* in_sizes, int n_in,
                              void* d_out, int out_size, void* d_ws, size_t ws_size,
                              hipStream_t stream) {
  const float* x = (const float*)d_in[0];
  const float* y = (const float*)d_in[1];
  short* xn = (short*)d_ws;
  short* yn = xn + N_ROWS * DIM;
  float* rowsum = (float*)(yn + N_ROWS * DIM);
  float* out = (float*)d_out;

  size_t need = (size_t)2 * N_ROWS * DIM * sizeof(short) + 3 * N_ROWS * sizeof(float);
  if (ws_size < need) return;

  k_normalize<<<4096, 256, 0, stream>>>(x, y, xn, yn, rowsum, out);
  k_gemm<<<8256, 256, 0, stream>>>(xn, yn, rowsum);
  k_reduce<<<256, 256, 0, stream>>>(xn, yn, rowsum, out);
}

// Round 13
// 189.323 us; speedup vs baseline: 1.0687x; 1.0687x over previous
//
#include <hip/hip_runtime.h>
#include <hip/hip_bf16.h>

// ContrastiveLoss on MI355X.
// ws layout (requires ws_size >= 8MB + 96KB + 4B):
//   [0, 4MB)   xn bf16 [8192][256]
//   [4MB, 8MB) yn bf16 [8192][256]
//   then       rowsum f32 [3][8192]; possum f32 [1]

#define N_ROWS 8192
#define DIM 256
#define EPSF 1e-8f
#define BT 256          // block tile (256x256)
#define BK 32           // K-step
#define KSTEPS 8        // DIM/BK
#define SLOTS 2048      // 16B slots per K-step buffer (A:1024 + B:1024)

typedef __attribute__((ext_vector_type(8))) short bf16x8;
typedef __attribute__((ext_vector_type(4))) float f32x4;
typedef __attribute__((ext_vector_type(4))) short short4v;

__device__ __forceinline__ short f2bf(float f) {
  unsigned u = __float_as_uint(f);
  unsigned r = (u + 0x7fffu + ((u >> 16) & 1u)) >> 16;  // RNE
  return (short)r;
}
__device__ __forceinline__ float bf2f(short s) {
  return __uint_as_float(((unsigned)(unsigned short)s) << 16);
}

typedef const __attribute__((address_space(1))) void g_void;
typedef __attribute__((address_space(3))) void s_void;
__device__ __forceinline__ void gld_lds16(const void* g, void* l) {
  __builtin_amdgcn_global_load_lds((g_void*)g, (s_void*)l, 16, 0, 0);
}

// ---- Kernel 1: row-normalize x,y -> bf16; zero rowsum/out/possum ----
__global__ void k_normalize(const float* __restrict__ x, const float* __restrict__ y,
                            short* __restrict__ xn, short* __restrict__ yn,
                            float* __restrict__ rowsum, float* __restrict__ out) {
  if (blockIdx.x < 96) rowsum[blockIdx.x * 256 + threadIdx.x] = 0.f;  // 24576
  if (blockIdx.x == 96 && threadIdx.x == 0) out[0] = 0.f;
  if (blockIdx.x == 97 && threadIdx.x == 0) rowsum[3 * N_ROWS] = 0.f;  // possum

  int wave = threadIdx.x >> 6;
  int lane = threadIdx.x & 63;
  int row = blockIdx.x * 4 + wave;  // 0..16383
  const float* src; short* dst; int r;
  if (row < N_ROWS) { src = x; dst = xn; r = row; }
  else              { src = y; dst = yn; r = row - N_ROWS; }
  const float4 v = *(const float4*)(src + r * DIM + lane * 4);
  float ss = v.x * v.x + v.y * v.y + v.z * v.z + v.w * v.w;
  #pragma unroll
  for (int m = 1; m < 64; m <<= 1) ss += __shfl_xor(ss, m, 64);
  float scale = 1.0f / (sqrtf(ss) + EPSF);
  short4v o;
  o.x = f2bf(v.x * scale); o.y = f2bf(v.y * scale);
  o.z = f2bf(v.z * scale); o.w = f2bf(v.w * scale);
  *(short4v*)(dst + r * DIM + lane * 4) = o;
}

// ------- Kernel 2: 256^2 tile, 8 waves (wave 128x64), counted-vmcnt pipeline -------
// 4 K-step LDS buffers (no aliasing: iter t reads buf[t&3], stages t+3 into
// buf[(t-1)&3] gated by this iter's barrier). One raw s_barrier per K-step,
// fused with counted vmcnt(8/4/0) -- loads stay in flight across barriers
// (T4; never vmcnt(0) mid-loop). T5 setprio around MFMA cluster.
// Swizzle: LDS slot (row,c) holds global chunk c^((row>>1)&3) (2-way = free).
// Grid 2080 = 2*528 upper-tri + 1024 xy = 8*260 (exact XCD balance).
// Diagonal tiles also bank pos = sum(diag sim) pre-exp into possum.
__global__ __launch_bounds__(512, 2) void k_gemm(const short* __restrict__ xn,
                                                 const short* __restrict__ yn,
                                                 float* __restrict__ rowsum) {
  __shared__ __align__(16) short As[4][1024 * 8];  // 4 bufs x 16KB
  __shared__ __align__(16) short Bs[4][1024 * 8];  // 4 bufs x 16KB
  __shared__ float redbuf[512];                    // rows [0:256), cols [256:512)
  __shared__ float possum_s;

  int bid = blockIdx.x;
  int swz = (bid & 7) * 260 + (bid >> 3);   // XCD-chunked, bijective (2080%8==0)

  int pair, mb, nb;
  if (swz < 1056) {                          // symmetric pairs, 32x32 upper tri
    pair = (swz < 528) ? 0 : 2;
    int t = (swz < 528) ? swz : swz - 528;
    int r = 0;
    while (t >= 32 - r) { t -= 32 - r; ++r; }  // block-uniform, <=32 iters
    mb = r; nb = r + t;
  } else {                                   // xy: full 32x32
    pair = 1;
    int t = swz - 1056;
    mb = t >> 5; nb = t & 31;
  }

  const short* Ap = (pair == 2) ? yn : xn;
  const short* Bp = (pair == 0) ? xn : yn;
  const short* Abase = Ap + mb * BT * DIM;
  const short* Bbase = Bp + nb * BT * DIM;

  int tid = threadIdx.x;
  int lane = tid & 63;
  int wid = tid >> 6;        // 0..7
  int wm = wid >> 2;         // 0..1 -> rows [wm*128, +128)
  int wn = wid & 3;          // 0..3 -> cols [wn*64, +64)

  redbuf[tid] = 0.f;
  if (tid == 0) possum_s = 0.f;

  f32x4 acc[8][4];
  #pragma unroll
  for (int i = 0; i < 8; ++i)
    #pragma unroll
    for (int j = 0; j < 4; ++j) acc[i][j] = (f32x4){0.f, 0.f, 0.f, 0.f};

  // stage K-step t into buf[t&3]: A,B each 1024 16B-slots; slot (row,c)
  // holds global chunk c ^ ((row>>1)&3); linear LDS dest (rule #21)
  auto stage = [&](int t) {
    int buf = t & 3, koff = t * BK;
    #pragma unroll
    for (int i = 0; i < 2; ++i) {
      int s = i * 512 + tid;                 // 16B slot
      int row = s >> 2, c = s & 3;
      int cs = c ^ ((row >> 1) & 3);
      gld_lds16(Abase + row * DIM + koff + cs * 8, &As[buf][s * 8]);
    }
    #pragma unroll
    for (int i = 0; i < 2; ++i) {
      int s = i * 512 + tid;
      int row = s >> 2, c = s & 3;
      int cs = c ^ ((row >> 1) & 3);
      gld_lds16(Bbase + row * DIM + koff + cs * 8, &Bs[buf][s * 8]);
    }
  };

  int fslot = (lane >> 4) ^ ((lane >> 1) & 3);  // swizzled k-chunk slot

  auto compute = [&](int t) {
    int buf = t & 3;
    bf16x8 a[8], b[4];
    #pragma unroll
    for (int mi = 0; mi < 8; ++mi) {
      int row = wm * 128 + mi * 16 + (lane & 15);
      a[mi] = *(const bf16x8*)(&As[buf][row * BK + fslot * 8]);
    }
    #pragma unroll
    for (int ni = 0; ni < 4; ++ni) {
      int row = wn * 64 + ni * 16 + (lane & 15);
      b[ni] = *(const bf16x8*)(&Bs[buf][row * BK + fslot * 8]);
    }
    __builtin_amdgcn_s_setprio(1);
    #pragma unroll
    for (int mi = 0; mi < 8; ++mi)
      #pragma unroll
      for (int ni = 0; ni < 4; ++ni)
        acc[mi][ni] = __builtin_amdgcn_mfma_f32_16x16x32_bf16(a[mi], b[ni], acc[mi][ni], 0, 0, 0);
    __builtin_amdgcn_s_setprio(0);
  };

  // prologue: 3 K-steps in flight (12 loads/thread)
  stage(0); stage(1); stage(2);

  // counted-vmcnt pipeline; vmcnt literal = 4*(steps in flight - 1)
#define ITER(T, VM)                                                      \
  asm volatile("s_waitcnt vmcnt(" #VM ")\n\ts_barrier" ::: "memory");    \
  if ((T) + 3 < KSTEPS) stage((T) + 3);                                  \
  compute(T);
  ITER(0, 8) ITER(1, 8) ITER(2, 8) ITER(3, 8) ITER(4, 8) ITER(5, 8)
  ITER(6, 4) ITER(7, 0)
#undef ITER

  // ---- epilogue ----
  // C frag layout (m89): col = lane&15, row = (lane>>4)*4 + r
  // local row = wm*128 + mi*16 + (lane>>4)*4 + r; col = wn*64 + ni*16 + (lane&15)
  bool diag = (mb == nb);
  if (diag) {  // bank positives (pre-exp)
    float ps = 0.f;
    #pragma unroll
    for (int mi = 0; mi < 8; ++mi)
      #pragma unroll
      for (int ni = 0; ni < 4; ++ni)
        #pragma unroll
        for (int r = 0; r < 4; ++r) {
          int rr = wm * 128 + mi * 16 + (lane >> 4) * 4 + r;
          int cc = wn * 64 + ni * 16 + (lane & 15);
          if (rr == cc) ps += acc[mi][ni][r];
        }
    if (ps != 0.f) atomicAdd(&possum_s, ps);
  }

  #pragma unroll
  for (int mi = 0; mi < 8; ++mi)
    #pragma unroll
    for (int ni = 0; ni < 4; ++ni)
      #pragma unroll
      for (int r = 0; r < 4; ++r)
        acc[mi][ni][r] = __expf(acc[mi][ni][r]);

  float rs[8][4];
  #pragma unroll
  for (int mi = 0; mi < 8; ++mi)
    #pragma unroll
    for (int r = 0; r < 4; ++r)
      rs[mi][r] = acc[mi][0][r] + acc[mi][1][r] + acc[mi][2][r] + acc[mi][3][r];
  #pragma unroll
  for (int m = 1; m < 16; m <<= 1)
    #pragma unroll
    for (int mi = 0; mi < 8; ++mi)
      #pragma unroll
      for (int r = 0; r < 4; ++r) rs[mi][r] += __shfl_xor(rs[mi][r], m, 64);
  if ((lane & 15) == 0) {
    int rloc = wm * 128 + (lane >> 4) * 4;
    #pragma unroll
    for (int mi = 0; mi < 8; ++mi)
      #pragma unroll
      for (int r = 0; r < 4; ++r)
        atomicAdd(&redbuf[rloc + mi * 16 + r], rs[mi][r]);   // 4-way (wn) combine
  }

  bool do_cols = (pair != 1) && (nb > mb);
  if (do_cols) {
    float cs[4];
    #pragma unroll
    for (int ni = 0; ni < 4; ++ni) {
      cs[ni] = 0.f;
      #pragma unroll
      for (int mi = 0; mi < 8; ++mi)
        #pragma unroll
        for (int r = 0; r < 4; ++r) cs[ni] += acc[mi][ni][r];
    }
    #pragma unroll
    for (int m = 16; m < 64; m <<= 1)
      #pragma unroll
      for (int ni = 0; ni < 4; ++ni) cs[ni] += __shfl_xor(cs[ni], m, 64);
    if (lane < 16) {
      #pragma unroll
      for (int ni = 0; ni < 4; ++ni)
        atomicAdd(&redbuf[256 + wn * 64 + ni * 16 + lane], cs[ni]);  // 2-way (wm)
    }
  }
  __syncthreads();

  if (tid < 256)
    atomicAdd(&rowsum[pair * N_ROWS + mb * BT + tid], redbuf[tid]);
  else if (do_cols)
    atomicAdd(&rowsum[pair * N_ROWS + nb * BT + (tid - 256)], redbuf[tid]);
  if (tid == 0 && diag && possum_s != 0.f)
    atomicAdd(&rowsum[3 * N_ROWS], possum_s);   // global possum
}

// ------- Kernel 3: out = sum(log(rowsum)) - possum -------
__global__ void k_reduce(const float* __restrict__ rowsum, float* __restrict__ out) {
  int tid = threadIdx.x, lane = tid & 63, wid = tid >> 6;
  float v = logf(rowsum[blockIdx.x * 256 + tid]);
  #pragma unroll
  for (int m = 1; m < 64; m <<= 1) v += __shfl_xor(v, m, 64);
  __shared__ float tmp[4];
  if (lane == 0) tmp[wid] = v;
  __syncthreads();
  if (tid == 0) {
    float s = tmp[0] + tmp[1] + tmp[2] + tmp[3];
    if (blockIdx.x == 0) s -= rowsum[3 * N_ROWS];  // possum
    atomicAdd(out, s);
  }
}

extern "C" void kernel_launch(void* const* d_in, const int* in_sizes, int n_in,
                              void* d_out, int out_size, void* d_ws, size_t ws_size,
                              hipStream_t stream) {
  const float* x = (const float*)d_in[0];
  const float* y = (const float*)d_in[1];
  short* xn = (short*)d_ws;
  short* yn = xn + N_ROWS * DIM;
  float* rowsum = (float*)(yn + N_ROWS * DIM);
  float* out = (float*)d_out;

  size_t need = (size_t)2 * N_ROWS * DIM * sizeof(short) + (3 * N_ROWS + 1) * sizeof(float);
  if (ws_size < need) return;

  k_normalize<<<4096, 256, 0, stream>>>(x, y, xn, yn, rowsum, out);
  k_gemm<<<2080, 512, 0, stream>>>(xn, yn, rowsum);
  k_reduce<<<96, 256, 0, stream>>>(rowsum, out);
}